// Round 7
// baseline (308.881 us; speedup 1.0000x reference)
//
#include <hip/hip_runtime.h>
#include <math.h>

// Problem constants
#define B_DIM 8
#define T_DIM 2048
#define C_DIM 1024
#define HS_DIM 128
#define VD 256
#define M_DIM (B_DIM * T_DIM)            // 16384 rows
#define QK_ELEMS (M_DIM * HS_DIM)        // 2,097,152 elems per (q|k) term
#define SCALE 0.088388347648318447f      // 1/sqrt(128)
#define LOG_THETA 9.210340371976184f     // ln(10000)

// workspace layout (ushort units)
#define QB_OFF   0u
#define KB_OFF   4194304u
#define VT_OFF   8388608u
#define WT_OFF   12582912u
#define XBH_OFF  13369344u               // x-bf16 rows 8192..16383
#define LAM_OFF  21757952u
#define XSPLIT_ELEMS 8388608u            // rows 0..8191 of x-bf16 live in d_out

typedef short s8v   __attribute__((ext_vector_type(8)));   // 8 bf16 (4 VGPRs)
typedef float f32x4 __attribute__((ext_vector_type(4)));
typedef float f32x16 __attribute__((ext_vector_type(16)));

// ---------- helpers ----------
__device__ __forceinline__ unsigned int bf16_rne(float f) {
    unsigned int u = __float_as_uint(f);
    return (u + 0x7fffu + ((u >> 16) & 1u)) >> 16;
}
__device__ __forceinline__ unsigned int pack_bf2(float lo, float hi) {
    return bf16_rne(lo) | (bf16_rne(hi) << 16);
}
__device__ __forceinline__ void async_cp16(const unsigned short* g, unsigned short* l) {
    __builtin_amdgcn_global_load_lds(
        (const __attribute__((address_space(1))) unsigned int*)g,
        (__attribute__((address_space(3))) unsigned int*)l, 16, 0, 0);
}

// ---------- kernel 1: lambda coefficients ----------
__global__ void lam_kernel(const float* __restrict__ lq, const float* __restrict__ lk,
                           const int* __restrict__ lidx, float* __restrict__ lam_out) {
    int t = threadIdx.x; // 64 threads = 1 wave
    float s0 = expf(lq[t] * lk[t]) + expf(lq[t + 64] * lk[t + 64]);
    float s1 = expf(lq[128 + t] * lk[128 + t]) + expf(lq[192 + t] * lk[192 + t]);
    #pragma unroll
    for (int off = 32; off > 0; off >>= 1) {
        s0 += __shfl_down(s0, off);
        s1 += __shfl_down(s1, off);
    }
    if (t == 0) {
        float e0 = s0 * (1.0f / 128.0f);
        float e1 = s1 * (1.0f / 128.0f);
        float li = 0.8f - 0.6f * expf(-0.3f * ((float)lidx[0] - 1.0f));
        lam_out[0] = e0 + li;            // +lam0
        lam_out[1] = -(e1 - e0 + li);    // -lam1
    }
}

// ---------- kernel 2a: cast x -> bf16 (split across d_out scratch + ws) ----------
__global__ __launch_bounds__(256) void cast_x_kernel(const float* __restrict__ x,
                                                     unsigned short* __restrict__ lo,
                                                     unsigned short* __restrict__ hi) {
    const size_t i8 = ((size_t)blockIdx.x * 256 + threadIdx.x) * 8;
    float4 a = *(const float4*)(x + i8);
    float4 b = *(const float4*)(x + i8 + 4);
    uint4 u;
    u.x = pack_bf2(a.x, a.y); u.y = pack_bf2(a.z, a.w);
    u.z = pack_bf2(b.x, b.y); u.w = pack_bf2(b.z, b.w);
    unsigned short* dst = (i8 < XSPLIT_ELEMS) ? (lo + i8) : (hi + (i8 - XSPLIT_ELEMS));
    *(uint4*)dst = u;
}

// ---------- kernel 2b: build Wt[768][1024] bf16 (transposed, concatenated) ----
__global__ __launch_bounds__(256) void cast_wt_kernel(
    const float* __restrict__ Wq, const float* __restrict__ Wk,
    const float* __restrict__ Wv, unsigned short* __restrict__ wt) {
    __shared__ float tile[32][33];
    const int t = threadIdx.x;
    const int n0 = blockIdx.x * 32;
    const int k0 = blockIdx.y * 32;
    const int seg = n0 >> 7;
    const int nl = t & 31;
    const int ng = n0 + nl;
    const float* src; int ld;
    if (seg < 2)      { src = Wq + (size_t)seg * (C_DIM * HS_DIM) + (ng & 127); ld = 128; }
    else if (seg < 4) { src = Wk + (size_t)(seg - 2) * (C_DIM * HS_DIM) + (ng & 127); ld = 128; }
    else              { src = Wv + (ng - 512); ld = 256; }
    #pragma unroll
    for (int rep = 0; rep < 4; ++rep) {
        int kl = (t >> 5) + rep * 8;
        tile[kl][nl] = src[(size_t)(k0 + kl) * ld];
    }
    __syncthreads();
    unsigned int* wt32 = (unsigned int*)wt;
    #pragma unroll
    for (int rep = 0; rep < 2; ++rep) {
        int nl2 = (t >> 4) + rep * 16;
        int k2 = (t & 15) * 2;
        unsigned int u = pack_bf2(tile[k2][nl2], tile[k2 + 1][nl2]);
        wt32[((size_t)(n0 + nl2) * 1024 + k0 + k2) >> 1] = u;
    }
}

// ---------- kernel 2c: bf16 MFMA GEMM + RoPE / V-transpose epilogue ----------
__global__ __launch_bounds__(256) void gemm_kernel(
    const unsigned short* __restrict__ xlo, const unsigned short* __restrict__ xhi,
    const unsigned short* __restrict__ wt,
    unsigned short* __restrict__ qo, unsigned short* __restrict__ ko,
    unsigned short* __restrict__ vo) {
    __shared__ unsigned short As[128 * 32];   // 8 KB, row-major [128][32]
    __shared__ unsigned short Bs[128 * 32];   // 8 KB, row-major [128][32]

    const int t = threadIdx.x;
    const int wv = t >> 6, lane = t & 63;
    const int quad = lane >> 4, l15 = lane & 15;
    const int m0 = blockIdx.x * 128;
    const int n0 = blockIdx.y * 128;
    const int wr = wv >> 1, wc = wv & 1;

    const unsigned short* xbase = (m0 < 8192)
        ? (xlo + (size_t)m0 * C_DIM) : (xhi + (size_t)(m0 - 8192) * C_DIM);

    f32x4 acc[4][4];
    #pragma unroll
    for (int i = 0; i < 4; ++i)
        #pragma unroll
        for (int j = 0; j < 4; ++j) acc[i][j] = (f32x4){0.f, 0.f, 0.f, 0.f};

    const int srow = lane >> 2;
    const int skof = (lane & 3) * 8;

    for (int k0 = 0; k0 < C_DIM; k0 += 32) {
        #pragma unroll
        for (int j = 0; j < 2; ++j) {
            const int c = wv * 2 + j;
            async_cp16(xbase + (size_t)(c * 16 + srow) * C_DIM + k0 + skof, As + c * 512);
        }
        #pragma unroll
        for (int j = 0; j < 2; ++j) {
            const int c = wv * 2 + j;
            async_cp16(wt + (size_t)(n0 + c * 16 + srow) * C_DIM + k0 + skof, Bs + c * 512);
        }
        __syncthreads();
        s8v af[4], bf[4];
        #pragma unroll
        for (int i = 0; i < 4; ++i)
            af[i] = *(const s8v*)&As[(wr * 64 + i * 16 + l15) * 32 + quad * 8];
        #pragma unroll
        for (int j = 0; j < 4; ++j)
            bf[j] = *(const s8v*)&Bs[(wc * 64 + j * 16 + l15) * 32 + quad * 8];
        #pragma unroll
        for (int i = 0; i < 4; ++i)
            #pragma unroll
            for (int j = 0; j < 4; ++j)
                acc[i][j] = __builtin_amdgcn_mfma_f32_16x16x32_bf16(af[i], bf[j], acc[i][j], 0, 0, 0);
        __syncthreads();
    }

    const int seg = n0 >> 7;   // 0..5
    if (seg < 4) {
        unsigned short* dstbuf = ((seg < 2) ? qo : ko) + (size_t)(seg & 1) * QK_ELEMS;
        float freqj[4];
        #pragma unroll
        for (int j = 0; j < 4; ++j) {
            const int d = wc * 64 + j * 16 + l15;
            freqj[j] = __expf((float)(d >> 1) * (-LOG_THETA / 64.f));
        }
        const int odd = lane & 1;
        #pragma unroll
        for (int i = 0; i < 4; ++i) {
            #pragma unroll
            for (int e = 0; e < 4; ++e) {
                const int m = m0 + wr * 64 + i * 16 + quad * 4 + e;
                const float trow = (float)(m & (T_DIM - 1));
                unsigned int* p32 = (unsigned int*)(dstbuf + (size_t)m * HS_DIM);
                #pragma unroll
                for (int j = 0; j < 4; ++j) {
                    const int d = wc * 64 + j * 16 + l15;
                    const float val = acc[i][j][e];
                    const float other = __shfl_xor(val, 1);
                    float sn_, cs_;
                    __sincosf(trow * freqj[j], &sn_, &cs_);
                    const float out = val * cs_ + (odd ? other * sn_ : -other * sn_);
                    const float out2 = __shfl_xor(out, 1);
                    if (!odd) p32[d >> 1] = pack_bf2(out, out2);
                }
            }
        }
    } else {
        const int bq = m0 >> 11;
        const int tbase = m0 & (T_DIM - 1);
        unsigned int* vT32 = (unsigned int*)vo;
        #pragma unroll
        for (int j = 0; j < 4; ++j) {
            const int d = (seg - 4) * 128 + wc * 64 + j * 16 + l15;
            const size_t rowbase = (size_t)(bq * VD + d) * (T_DIM / 2); // u32 units
            #pragma unroll
            for (int i = 0; i < 4; ++i) {
                const int tok = tbase + wr * 64 + i * 16 + quad * 4;
                uint2 u;
                u.x = pack_bf2(acc[i][j][0], acc[i][j][1]);
                u.y = pack_bf2(acc[i][j][2], acc[i][j][3]);
                *(uint2*)&vT32[rowbase + (tok >> 1)] = u;
            }
        }
    }
}

// ---------- kernel 3: dual-term causal attention, barrier-free K-loop ----------
// Grid: 512 = 64 strips x 8 batches (b = id&7 pins batch to an XCD; its
// Q+K+V = 3 MB fits the 4 MB per-XCD L2). Block: 4 waves, each autonomous:
// wave = (term, kh); wave owns 32-key tiles it = kh, kh+2, ... and a partial
// O[32q x 256d] in 128 VGPRs. K and V fragments are loaded DIRECTLY from
// global (L2-resident) -- no LDS staging, no __syncthreads in the K-loop.
// P does a same-wave LDS round-trip (C-layout -> A-layout transpose).
// Partials are combined across kh and term in the LDS epilogue.
// NOTE (round-5 bug): waves have DIFFERENT trip counts, and Lsum overlays
// waves 0/1's private P region -- a barrier between the K-loop and the Lsum
// publication is mandatory or a fast wave corrupts a slow wave's live P.
#define PSTR 40                     // P row stride (ushort), 16B-aligned rows
#define OSTR 260                    // O combine row stride (fp32 words)
#define OL0_OFF 0
#define OL1_OFF 33280
#define P_OFF   66560
#define SM_TOTAL 76800

__global__ __launch_bounds__(256, 2) void attn_kernel(
    const unsigned short* __restrict__ qg, const unsigned short* __restrict__ kg,
    const unsigned short* __restrict__ vg, const float* __restrict__ lam,
    float* __restrict__ outp) {
    __shared__ __align__(16) unsigned char smem[SM_TOTAL];
    float* Ol0 = (float*)(smem + OL0_OFF);                 // [32][260] term-0
    float* Ol1 = (float*)(smem + OL1_OFF);                 // [32][260] term-1
    float* Lsum = (float*)(smem + P_OFF);                  // [2][2][32] overlays P

    const int t = threadIdx.x;
    const int id = blockIdx.x;
    const int b = id & 7;                  // batch -> XCD round-robin
    const int sidx = id >> 3;              // 0..63
    const int strip = (sidx < 32) ? (63 - sidx) : (sidx - 32); // pair heavy+light
    const int q0 = strip * 32;
    const int nt32 = strip + 1;            // 32-key tiles

    const int w = t >> 6, lane = t & 63;
    const int l31 = lane & 31, lh = lane >> 5;
    const int term = w >> 1;
    const int kh = w & 1;                  // key-tile parity owned by this wave

    unsigned short* Pw = (unsigned short*)(smem + P_OFF) + w * (32 * PSTR); // 2.5 KB/wave

    const float cn = lam[term];            // lam[1] carries the minus sign

    // Q A-frags: A[row=l31][k=ks*16+lh*8+j]
    const unsigned short* qbase = qg
        + ((size_t)(term * B_DIM + b) * T_DIM + q0 + l31) * HS_DIM + lh * 8;
    s8v qa[8];
    #pragma unroll
    for (int ks = 0; ks < 8; ++ks)
        qa[ks] = *(const s8v*)(qbase + ks * 16);

    // K B-frags source: B[col=l31(key)][k=ks*16+lh*8+j]
    const unsigned short* kbase = kg
        + ((size_t)(term * B_DIM + b) * T_DIM + l31) * HS_DIM + lh * 8;
    // V B-frags source: B[col=l31 within d-tile][k=token]
    const unsigned short* vbase = vg
        + ((size_t)(b * VD + l31) * T_DIM) + lh * 8;

    f32x16 o[8];
    #pragma unroll
    for (int dt = 0; dt < 8; ++dt)
        #pragma unroll
        for (int r = 0; r < 16; ++r) o[dt][r] = 0.f;
    float l_acc[16];
    #pragma unroll
    for (int r = 0; r < 16; ++r) l_acc[r] = 0.f;

    for (int it = kh; it < nt32; it += 2) {
        const int s0 = it * 32;
        // ---- QK: S[32q x 32k], K frags straight from L2 ----
        s8v kf[8];
        #pragma unroll
        for (int ks = 0; ks < 8; ++ks)
            kf[ks] = *(const s8v*)(kbase + (size_t)s0 * HS_DIM + ks * 16);
        f32x16 sc;
        #pragma unroll
        for (int r = 0; r < 16; ++r) sc[r] = 0.f;
        #pragma unroll
        for (int ks = 0; ks < 8; ++ks)
            sc = __builtin_amdgcn_mfma_f32_32x32x16_bf16(qa[ks], kf[ks], sc, 0, 0, 0);

        // ---- exp (+ causal mask on the diagonal tile only), P -> LDS ----
        if (it != strip) {
            #pragma unroll
            for (int r = 0; r < 16; ++r) {
                const int row = (r & 3) + 8 * (r >> 2) + 4 * lh;
                const float p = __expf(sc[r] * SCALE);
                l_acc[r] += p;
                Pw[row * PSTR + l31] = (unsigned short)bf16_rne(p);
            }
        } else {
            const int key = s0 + l31;
            #pragma unroll
            for (int r = 0; r < 16; ++r) {
                const int row = (r & 3) + 8 * (r >> 2) + 4 * lh;
                const float p = (key <= q0 + row) ? __expf(sc[r] * SCALE) : 0.f;
                l_acc[r] += p;
                Pw[row * PSTR + l31] = (unsigned short)bf16_rne(p);
            }
        }
        asm volatile("" ::: "memory");  // same-wave LDS write -> read ordering

        // ---- PV: O[32q x 256d] += P[32x32] @ V[32x256], V frags from L2 ----
        const s8v pa0 = *(const s8v*)&Pw[l31 * PSTR + lh * 8];
        const s8v pa1 = *(const s8v*)&Pw[l31 * PSTR + 16 + lh * 8];
        #pragma unroll
        for (int dt = 0; dt < 8; ++dt) {
            const unsigned short* vrow = vbase + (size_t)(dt * 32) * T_DIM + s0;
            const s8v vb0 = *(const s8v*)(vrow);
            const s8v vb1 = *(const s8v*)(vrow + 16);
            o[dt] = __builtin_amdgcn_mfma_f32_32x32x16_bf16(pa0, vb0, o[dt], 0, 0, 0);
            o[dt] = __builtin_amdgcn_mfma_f32_32x32x16_bf16(pa1, vb1, o[dt], 0, 0, 0);
        }
    }

    // ---- ALL waves must finish reading their P before Lsum overlays it ----
    __syncthreads();

    // ---- l: reduce over 32 key-lanes, publish per-(term,kh), combine ----
    #pragma unroll
    for (int r = 0; r < 16; ++r) {
        float lt = l_acc[r];
        #pragma unroll
        for (int off = 1; off < 32; off <<= 1) lt += __shfl_xor(lt, off);
        if (l31 == 0) {
            const int row = (r & 3) + 8 * (r >> 2) + 4 * lh;
            Lsum[(term * 2 + kh) * 32 + row] = lt;
        }
    }
    __syncthreads();
    float inv[16];
    #pragma unroll
    for (int r = 0; r < 16; ++r) {
        const int row = (r & 3) + 8 * (r >> 2) + 4 * lh;
        inv[r] = cn / (Lsum[(term * 2 + 0) * 32 + row] + Lsum[(term * 2 + 1) * 32 + row]);
    }

    // ---- combine kh partials per term (kh0 writes, kh1 adds) ----
    float* Ob = term ? Ol1 : Ol0;
    if (kh == 0) {
        #pragma unroll
        for (int dt = 0; dt < 8; ++dt)
            #pragma unroll
            for (int r = 0; r < 16; ++r) {
                const int row = (r & 3) + 8 * (r >> 2) + 4 * lh;
                Ob[row * OSTR + dt * 32 + l31] = o[dt][r] * inv[r];
            }
    }
    __syncthreads();
    if (kh == 1) {
        #pragma unroll
        for (int dt = 0; dt < 8; ++dt)
            #pragma unroll
            for (int r = 0; r < 16; ++r) {
                const int row = (r & 3) + 8 * (r >> 2) + 4 * lh;
                Ob[row * OSTR + dt * 32 + l31] += o[dt][r] * inv[r];
            }
    }
    __syncthreads();

    // ---- store: out = term0 + term1 ----
    #pragma unroll
    for (int rep = 0; rep < 8; ++rep) {
        int idx = t + rep * 256;           // 32 rows x 64 float4
        int row = idx >> 6, c4 = idx & 63;
        float4 a = *(const float4*)&Ol0[row * OSTR + c4 * 4];
        float4 c = *(const float4*)&Ol1[row * OSTR + c4 * 4];
        float4 val = make_float4(a.x + c.x, a.y + c.y, a.z + c.z, a.w + c.w);
        *(float4*)&outp[((size_t)(b * T_DIM + q0 + row)) * VD + c4 * 4] = val;
    }
}

extern "C" void kernel_launch(void* const* d_in, const int* in_sizes, int n_in,
                              void* d_out, int out_size, void* d_ws, size_t ws_size,
                              hipStream_t stream) {
    const float* x  = (const float*)d_in[0];
    const float* Wq = (const float*)d_in[1];
    const float* Wk = (const float*)d_in[2];
    const float* Wv = (const float*)d_in[3];
    const float* lq = (const float*)d_in[4];
    const float* lk = (const float*)d_in[5];
    const int* lidx = (const int*)d_in[6];

    unsigned short* ws = (unsigned short*)d_ws;
    unsigned short* qb   = ws + QB_OFF;    // [2][8][2048][128] bf16
    unsigned short* kb   = ws + KB_OFF;    // [2][8][2048][128] bf16
    unsigned short* vTb  = ws + VT_OFF;    // [8][256][2048] bf16
    unsigned short* wtb  = ws + WT_OFF;    // [768][1024] bf16
    unsigned short* xbhi = ws + XBH_OFF;   // x-bf16 rows 8192..16383
    float* lamb = (float*)(ws + LAM_OFF);
    unsigned short* xblo = (unsigned short*)d_out;  // scratch; attn overwrites d_out
    (void)ws_size; (void)in_sizes; (void)n_in; (void)out_size;

    lam_kernel<<<dim3(1), dim3(64), 0, stream>>>(lq, lk, lidx, lamb);
    cast_x_kernel<<<dim3(8192), dim3(256), 0, stream>>>(x, xblo, xbhi);
    cast_wt_kernel<<<dim3(24, 32), dim3(256), 0, stream>>>(Wq, Wk, Wv, wtb);
    gemm_kernel<<<dim3(128, 6), dim3(256), 0, stream>>>(xblo, xbhi, wtb, qb, kb, vTb);
    attn_kernel<<<dim3(512), dim3(256), 0, stream>>>(qb, kb, vTb, lamb, (float*)d_out);
}

// Round 8
// 234.212 us; speedup vs baseline: 1.3188x; 1.3188x over previous
//
#include <hip/hip_runtime.h>
#include <math.h>

// Problem constants
#define B_DIM 8
#define T_DIM 2048
#define C_DIM 1024
#define HS_DIM 128
#define VD 256
#define M_DIM (B_DIM * T_DIM)            // 16384 rows
#define QK_ELEMS (M_DIM * HS_DIM)        // 2,097,152 elems per (q|k) term
#define SCALE 0.088388347648318447f      // 1/sqrt(128)
#define LOG_THETA 9.210340371976184f     // ln(10000)

// workspace layout (ushort units)
#define QB_OFF   0u
#define KB_OFF   4194304u
#define VT_OFF   8388608u
#define WT_OFF   12582912u
#define XBH_OFF  13369344u               // x-bf16 rows 8192..16383
#define LAM_OFF  21757952u
#define XSPLIT_ELEMS 8388608u            // rows 0..8191 of x-bf16 live in d_out

typedef short s8v   __attribute__((ext_vector_type(8)));   // 8 bf16 (4 VGPRs)
typedef float f32x4 __attribute__((ext_vector_type(4)));
typedef float f32x16 __attribute__((ext_vector_type(16)));

// ---------- helpers ----------
__device__ __forceinline__ unsigned int bf16_rne(float f) {
    unsigned int u = __float_as_uint(f);
    return (u + 0x7fffu + ((u >> 16) & 1u)) >> 16;
}
__device__ __forceinline__ unsigned int pack_bf2(float lo, float hi) {
    return bf16_rne(lo) | (bf16_rne(hi) << 16);
}
__device__ __forceinline__ void async_cp16(const unsigned short* g, unsigned short* l) {
    __builtin_amdgcn_global_load_lds(
        (const __attribute__((address_space(1))) unsigned int*)g,
        (__attribute__((address_space(3))) unsigned int*)l, 16, 0, 0);
}

// ---------- kernel 1: lambda coefficients ----------
__global__ void lam_kernel(const float* __restrict__ lq, const float* __restrict__ lk,
                           const int* __restrict__ lidx, float* __restrict__ lam_out) {
    int t = threadIdx.x; // 64 threads = 1 wave
    float s0 = expf(lq[t] * lk[t]) + expf(lq[t + 64] * lk[t + 64]);
    float s1 = expf(lq[128 + t] * lk[128 + t]) + expf(lq[192 + t] * lk[192 + t]);
    #pragma unroll
    for (int off = 32; off > 0; off >>= 1) {
        s0 += __shfl_down(s0, off);
        s1 += __shfl_down(s1, off);
    }
    if (t == 0) {
        float e0 = s0 * (1.0f / 128.0f);
        float e1 = s1 * (1.0f / 128.0f);
        float li = 0.8f - 0.6f * expf(-0.3f * ((float)lidx[0] - 1.0f));
        lam_out[0] = e0 + li;            // +lam0
        lam_out[1] = -(e1 - e0 + li);    // -lam1
    }
}

// ---------- kernel 2a: cast x -> bf16 (split across d_out scratch + ws) ----------
__global__ __launch_bounds__(256) void cast_x_kernel(const float* __restrict__ x,
                                                     unsigned short* __restrict__ lo,
                                                     unsigned short* __restrict__ hi) {
    const size_t i8 = ((size_t)blockIdx.x * 256 + threadIdx.x) * 8;
    float4 a = *(const float4*)(x + i8);
    float4 b = *(const float4*)(x + i8 + 4);
    uint4 u;
    u.x = pack_bf2(a.x, a.y); u.y = pack_bf2(a.z, a.w);
    u.z = pack_bf2(b.x, b.y); u.w = pack_bf2(b.z, b.w);
    unsigned short* dst = (i8 < XSPLIT_ELEMS) ? (lo + i8) : (hi + (i8 - XSPLIT_ELEMS));
    *(uint4*)dst = u;
}

// ---------- kernel 2b: build Wt[768][1024] bf16 (transposed, concatenated) ----
__global__ __launch_bounds__(256) void cast_wt_kernel(
    const float* __restrict__ Wq, const float* __restrict__ Wk,
    const float* __restrict__ Wv, unsigned short* __restrict__ wt) {
    __shared__ float tile[32][33];
    const int t = threadIdx.x;
    const int n0 = blockIdx.x * 32;
    const int k0 = blockIdx.y * 32;
    const int seg = n0 >> 7;
    const int nl = t & 31;
    const int ng = n0 + nl;
    const float* src; int ld;
    if (seg < 2)      { src = Wq + (size_t)seg * (C_DIM * HS_DIM) + (ng & 127); ld = 128; }
    else if (seg < 4) { src = Wk + (size_t)(seg - 2) * (C_DIM * HS_DIM) + (ng & 127); ld = 128; }
    else              { src = Wv + (ng - 512); ld = 256; }
    #pragma unroll
    for (int rep = 0; rep < 4; ++rep) {
        int kl = (t >> 5) + rep * 8;
        tile[kl][nl] = src[(size_t)(k0 + kl) * ld];
    }
    __syncthreads();
    unsigned int* wt32 = (unsigned int*)wt;
    #pragma unroll
    for (int rep = 0; rep < 2; ++rep) {
        int nl2 = (t >> 4) + rep * 16;
        int k2 = (t & 15) * 2;
        unsigned int u = pack_bf2(tile[k2][nl2], tile[k2 + 1][nl2]);
        wt32[((size_t)(n0 + nl2) * 1024 + k0 + k2) >> 1] = u;
    }
}

// ---------- kernel 2c: bf16 MFMA GEMM + RoPE / V-transpose epilogue ----------
__global__ __launch_bounds__(256) void gemm_kernel(
    const unsigned short* __restrict__ xlo, const unsigned short* __restrict__ xhi,
    const unsigned short* __restrict__ wt,
    unsigned short* __restrict__ qo, unsigned short* __restrict__ ko,
    unsigned short* __restrict__ vo) {
    __shared__ unsigned short As[128 * 32];   // 8 KB, row-major [128][32]
    __shared__ unsigned short Bs[128 * 32];   // 8 KB, row-major [128][32]

    const int t = threadIdx.x;
    const int wv = t >> 6, lane = t & 63;
    const int quad = lane >> 4, l15 = lane & 15;
    const int m0 = blockIdx.x * 128;
    const int n0 = blockIdx.y * 128;
    const int wr = wv >> 1, wc = wv & 1;

    const unsigned short* xbase = (m0 < 8192)
        ? (xlo + (size_t)m0 * C_DIM) : (xhi + (size_t)(m0 - 8192) * C_DIM);

    f32x4 acc[4][4];
    #pragma unroll
    for (int i = 0; i < 4; ++i)
        #pragma unroll
        for (int j = 0; j < 4; ++j) acc[i][j] = (f32x4){0.f, 0.f, 0.f, 0.f};

    const int srow = lane >> 2;
    const int skof = (lane & 3) * 8;

    for (int k0 = 0; k0 < C_DIM; k0 += 32) {
        #pragma unroll
        for (int j = 0; j < 2; ++j) {
            const int c = wv * 2 + j;
            async_cp16(xbase + (size_t)(c * 16 + srow) * C_DIM + k0 + skof, As + c * 512);
        }
        #pragma unroll
        for (int j = 0; j < 2; ++j) {
            const int c = wv * 2 + j;
            async_cp16(wt + (size_t)(n0 + c * 16 + srow) * C_DIM + k0 + skof, Bs + c * 512);
        }
        __syncthreads();
        s8v af[4], bf[4];
        #pragma unroll
        for (int i = 0; i < 4; ++i)
            af[i] = *(const s8v*)&As[(wr * 64 + i * 16 + l15) * 32 + quad * 8];
        #pragma unroll
        for (int j = 0; j < 4; ++j)
            bf[j] = *(const s8v*)&Bs[(wc * 64 + j * 16 + l15) * 32 + quad * 8];
        #pragma unroll
        for (int i = 0; i < 4; ++i)
            #pragma unroll
            for (int j = 0; j < 4; ++j)
                acc[i][j] = __builtin_amdgcn_mfma_f32_16x16x32_bf16(af[i], bf[j], acc[i][j], 0, 0, 0);
        __syncthreads();
    }

    const int seg = n0 >> 7;   // 0..5
    if (seg < 4) {
        unsigned short* dstbuf = ((seg < 2) ? qo : ko) + (size_t)(seg & 1) * QK_ELEMS;
        float freqj[4];
        #pragma unroll
        for (int j = 0; j < 4; ++j) {
            const int d = wc * 64 + j * 16 + l15;
            freqj[j] = __expf((float)(d >> 1) * (-LOG_THETA / 64.f));
        }
        const int odd = lane & 1;
        #pragma unroll
        for (int i = 0; i < 4; ++i) {
            #pragma unroll
            for (int e = 0; e < 4; ++e) {
                const int m = m0 + wr * 64 + i * 16 + quad * 4 + e;
                const float trow = (float)(m & (T_DIM - 1));
                unsigned int* p32 = (unsigned int*)(dstbuf + (size_t)m * HS_DIM);
                #pragma unroll
                for (int j = 0; j < 4; ++j) {
                    const int d = wc * 64 + j * 16 + l15;
                    const float val = acc[i][j][e];
                    const float other = __shfl_xor(val, 1);
                    float sn_, cs_;
                    __sincosf(trow * freqj[j], &sn_, &cs_);
                    const float out = val * cs_ + (odd ? other * sn_ : -other * sn_);
                    const float out2 = __shfl_xor(out, 1);
                    if (!odd) p32[d >> 1] = pack_bf2(out, out2);
                }
            }
        }
    } else {
        const int bq = m0 >> 11;
        const int tbase = m0 & (T_DIM - 1);
        unsigned int* vT32 = (unsigned int*)vo;
        #pragma unroll
        for (int j = 0; j < 4; ++j) {
            const int d = (seg - 4) * 128 + wc * 64 + j * 16 + l15;
            const size_t rowbase = (size_t)(bq * VD + d) * (T_DIM / 2); // u32 units
            #pragma unroll
            for (int i = 0; i < 4; ++i) {
                const int tok = tbase + wr * 64 + i * 16 + quad * 4;
                uint2 u;
                u.x = pack_bf2(acc[i][j][0], acc[i][j][1]);
                u.y = pack_bf2(acc[i][j][2], acc[i][j][3]);
                *(uint2*)&vT32[rowbase + (tok >> 1)] = u;
            }
        }
    }
}

// ---------- kernel 3: dual-term causal attention, 32x32 bf16 MFMA ----------
// Round-4 proven structure (75.9 us): LDS-staged K/V, wave=(term,kh) for QK,
// wave=(term,dhalf) for PV, cross-wave P, 3 barriers/iter, Lsum cross-kh.
// This round's single change: staging via global_load_lds (width 16) with an
// XOR source-chunk swizzle (DMA needs unpadded contiguous LDS rows; swizzle
// restores conflict-free reads: bank = 4*((chunk)^(row&7))+w, distinct per
// 8-lane phase). Removes 16 ds_writes + 16 VGPR-roundtrip loads per wave-iter.
#define OSTR 260    // O combine stride (fp32 words)
#define PSTR 72     // P LDS row stride (ushort), padded (manual writes: pad OK)
#define K_OFF 0
#define V_OFF 32768
#define P_OFF 65536
#define SM_TOTAL 74752

__global__ __launch_bounds__(256, 2) void attn_kernel(
    const unsigned short* __restrict__ qg, const unsigned short* __restrict__ kg,
    const unsigned short* __restrict__ vg, const float* __restrict__ lam,
    float* __restrict__ outp) {
    __shared__ __align__(16) unsigned char smem[SM_TOTAL];
    unsigned short* Ks = (unsigned short*)(smem + K_OFF);  // [2][64][128] swizzled
    unsigned short* Vt = (unsigned short*)(smem + V_OFF);  // [256][64]    swizzled
    unsigned short* Ps = (unsigned short*)(smem + P_OFF);  // [2][32][72]
    float* Ol = (float*)smem;                              // [32][260] overlays K+V
    float* Lsum = (float*)(smem + P_OFF);                  // [2][2][32] overlays dead Ps

    const int t = threadIdx.x;
    const int id = blockIdx.x;
    const int b = id & 7;                  // batch -> XCD round-robin
    const int sidx = id >> 3;              // 0..63
    const int strip = (sidx < 32) ? (63 - sidx) : (sidx - 32); // complementary pairing
    const int q0 = strip * 32;
    const int nt = (strip >> 1) + 1;       // 64-key tiles

    const int w = t >> 6, lane = t & 63;
    const int l31 = lane & 31, lh = lane >> 5;
    const int term = w & 1;
    const int kh = w >> 1;                 // QK k-half / PV d-half

    const float cn = lam[term];            // lam[1] carries the minus sign

    // Q A-frags (32x32x16 layout: row=lane&31, k=lh*8+j), 8 k-steps in registers
    const unsigned short* qrow = qg
        + ((size_t)(term * B_DIM + b) * T_DIM + q0 + l31) * HS_DIM + lh * 8;
    s8v qa[8];
    #pragma unroll
    for (int ks = 0; ks < 8; ++ks)
        qa[ks] = *(const s8v*)(qrow + ks * 16);

    f32x16 o[4];
    #pragma unroll
    for (int dt = 0; dt < 4; ++dt)
        #pragma unroll
        for (int r = 0; r < 16; ++r) o[dt][r] = 0.f;
    float l_acc[16];
    #pragma unroll
    for (int r = 0; r < 16; ++r) l_acc[r] = 0.f;

    for (int it = 0; it < nt; ++it) {
        const int s0 = it * 64;
        // ---- DMA-stage K (2 terms x 64 keys x 128 els; 16B chunks, XOR swizzle)
        #pragma unroll
        for (int oo = 0; oo < 8; ++oo) {
            const int idx = (w * 8 + oo) * 64 + lane;   // chunk index 0..2047
            const int rfull = idx >> 4;                 // 0..127 (term*64+key)
            const int cc = idx & 15;
            const int ccs = cc ^ (rfull & 7);           // source-chunk swizzle
            const int n = rfull >> 6, r = rfull & 63;
            async_cp16(kg + ((size_t)(n * B_DIM + b) * T_DIM + s0 + r) * HS_DIM + ccs * 8,
                       Ks + (w * 8 + oo) * 512);
        }
        // ---- DMA-stage Vt (256 dims x 64 tokens; 16B chunks, XOR swizzle) ----
        #pragma unroll
        for (int oo = 0; oo < 8; ++oo) {
            const int idx = (w * 8 + oo) * 64 + lane;   // chunk index 0..2047
            const int d = idx >> 3;                     // 0..255
            const int cc = idx & 7;
            const int ccs = cc ^ (d & 7);
            async_cp16(vg + ((size_t)(b * VD + d) * T_DIM + s0) + ccs * 8,
                       Vt + (w * 8 + oo) * 512);
        }
        __syncthreads();

        // ---- QK: S[32q x 32k] for (term, khalf) ----
        f32x16 sc;
        #pragma unroll
        for (int r = 0; r < 16; ++r) sc[r] = 0.f;
        {
            const int krow = term * 64 + kh * 32 + l31;
            const unsigned short* kb = Ks + krow * 128;
            const int sw = krow & 7;
            #pragma unroll
            for (int ks = 0; ks < 8; ++ks) {
                s8v kf = *(const s8v*)(kb + (((ks * 2 + lh) ^ sw) << 3));
                sc = __builtin_amdgcn_mfma_f32_32x32x16_bf16(qa[ks], kf, sc, 0, 0, 0);
            }
        }
        // exp + P write (C/D 32x32: col=l31, row=(r&3)+8*(r>>2)+4*lh)
        const int key = s0 + kh * 32 + l31;
        #pragma unroll
        for (int r = 0; r < 16; ++r) {
            const int row = (r & 3) + 8 * (r >> 2) + 4 * lh;
            const float p = (key <= q0 + row) ? __expf(sc[r] * SCALE) : 0.f;
            l_acc[r] += p;
            Ps[(term * 32 + row) * PSTR + kh * 32 + l31] = (unsigned short)bf16_rne(p);
        }
        __syncthreads();

        // ---- PV: O[32q x 128d] += P[32x64] @ V[64x128] for (term, dhalf) ----
        #pragma unroll
        for (int ks = 0; ks < 4; ++ks) {
            s8v pa = *(const s8v*)&Ps[(term * 32 + l31) * PSTR + ks * 16 + lh * 8];
            #pragma unroll
            for (int dt = 0; dt < 4; ++dt) {
                const int d = kh * 128 + dt * 32 + l31;
                s8v vb = *(const s8v*)(Vt + d * 64 + (((ks * 2 + lh) ^ (d & 7)) << 3));
                o[dt] = __builtin_amdgcn_mfma_f32_32x32x16_bf16(pa, vb, o[dt], 0, 0, 0);
            }
        }
        __syncthreads();
    }

    // ---- finalize l: intra-wave reduce over 32 key-columns, then combine
    //      the two kh-wave partials per (term,row) through LDS ----
    #pragma unroll
    for (int r = 0; r < 16; ++r) {
        float lt = l_acc[r];
        #pragma unroll
        for (int off = 1; off < 32; off <<= 1) lt += __shfl_xor(lt, off);
        if (l31 == 0) {
            const int row = (r & 3) + 8 * (r >> 2) + 4 * lh;
            Lsum[(term * 2 + kh) * 32 + row] = lt;
        }
    }
    __syncthreads();
    float inv[16];
    #pragma unroll
    for (int r = 0; r < 16; ++r) {
        const int row = (r & 3) + 8 * (r >> 2) + 4 * lh;
        inv[r] = cn / (Lsum[(term * 2 + 0) * 32 + row] + Lsum[(term * 2 + 1) * 32 + row]);
    }

    // ---- combine terms via LDS overlay on K region ----
    if (term) {
        #pragma unroll
        for (int dt = 0; dt < 4; ++dt)
            #pragma unroll
            for (int r = 0; r < 16; ++r) {
                const int row = (r & 3) + 8 * (r >> 2) + 4 * lh;
                Ol[row * OSTR + kh * 128 + dt * 32 + l31] = o[dt][r] * inv[r];
            }
    }
    __syncthreads();
    if (!term) {
        #pragma unroll
        for (int dt = 0; dt < 4; ++dt)
            #pragma unroll
            for (int r = 0; r < 16; ++r) {
                const int row = (r & 3) + 8 * (r >> 2) + 4 * lh;
                Ol[row * OSTR + kh * 128 + dt * 32 + l31] += o[dt][r] * inv[r];
            }
    }
    __syncthreads();
    #pragma unroll
    for (int rep = 0; rep < 8; ++rep) {
        int idx = t + rep * 256;           // 32 rows x 64 float4
        int row = idx >> 6, c4 = idx & 63;
        float4 val = *(const float4*)&Ol[row * OSTR + c4 * 4];
        *(float4*)&outp[((size_t)(b * T_DIM + q0 + row)) * VD + c4 * 4] = val;
    }
}

extern "C" void kernel_launch(void* const* d_in, const int* in_sizes, int n_in,
                              void* d_out, int out_size, void* d_ws, size_t ws_size,
                              hipStream_t stream) {
    const float* x  = (const float*)d_in[0];
    const float* Wq = (const float*)d_in[1];
    const float* Wk = (const float*)d_in[2];
    const float* Wv = (const float*)d_in[3];
    const float* lq = (const float*)d_in[4];
    const float* lk = (const float*)d_in[5];
    const int* lidx = (const int*)d_in[6];

    unsigned short* ws = (unsigned short*)d_ws;
    unsigned short* qb   = ws + QB_OFF;    // [2][8][2048][128] bf16
    unsigned short* kb   = ws + KB_OFF;    // [2][8][2048][128] bf16
    unsigned short* vTb  = ws + VT_OFF;    // [8][256][2048] bf16
    unsigned short* wtb  = ws + WT_OFF;    // [768][1024] bf16
    unsigned short* xbhi = ws + XBH_OFF;   // x-bf16 rows 8192..16383
    float* lamb = (float*)(ws + LAM_OFF);
    unsigned short* xblo = (unsigned short*)d_out;  // scratch; attn overwrites d_out
    (void)ws_size; (void)in_sizes; (void)n_in; (void)out_size;

    lam_kernel<<<dim3(1), dim3(64), 0, stream>>>(lq, lk, lidx, lamb);
    cast_x_kernel<<<dim3(8192), dim3(256), 0, stream>>>(x, xblo, xbhi);
    cast_wt_kernel<<<dim3(24, 32), dim3(256), 0, stream>>>(Wq, Wk, Wv, wtb);
    gemm_kernel<<<dim3(128, 6), dim3(256), 0, stream>>>(xblo, xbhi, wtb, qb, kb, vTb);
    attn_kernel<<<dim3(512), dim3(256), 0, stream>>>(qb, kb, vTb, lamb, (float*)d_out);
}